// Round 10
// baseline (796.944 us; speedup 1.0000x reference)
//
#include <hip/hip_runtime.h>

typedef unsigned short ushort_t;
typedef unsigned int uint_t;

#define T_TOK 8192
#define HDIM 1024
#define IDIM 2048
#define NEXP 8
#define RPAD_MAX 10240                 // 8192 + 8*256 worst-case padded routed rows
#define TOTROWS (RPAD_MAX + T_TOK)     // 18432

using f32x4 = __attribute__((ext_vector_type(4))) float;
using s16x8 = __attribute__((ext_vector_type(8))) short;

#define SBAR() do { asm volatile("" ::: "memory"); __builtin_amdgcn_s_barrier(); asm volatile("" ::: "memory"); } while (0)
#define VMW(n) asm volatile("s_waitcnt vmcnt(" #n ")" ::: "memory")
#define LGKM(n) do { asm volatile("s_waitcnt lgkmcnt(" #n ")" ::: "memory"); __builtin_amdgcn_sched_barrier(0); } while (0)
#define SCHB() __builtin_amdgcn_sched_barrier(0)

__device__ __forceinline__ float b2f(ushort_t h) {
    return __uint_as_float(((uint_t)h) << 16);
}
__device__ __forceinline__ ushort_t f2bf(float f) {
    uint_t u = __float_as_uint(f);
    uint_t r = (u + 0x7FFFu + ((u >> 16) & 1u)) >> 16;
    return (ushort_t)r;
}
__device__ __forceinline__ void gload16(const void* g, void* l) {
    __builtin_amdgcn_global_load_lds(
        (const __attribute__((address_space(1))) void*)g,
        (__attribute__((address_space(3))) void*)l, 16, 0, 0);
}
// 2-D super-block scheduler (XCD locality): 4rt x 8ct rectangle per XCD round.
__device__ __forceinline__ void sbmap(int bid, int SBC, int NSB, int& rt, int& ct) {
    int x = bid & 7, j = bid >> 3;
    int r = j >> 5, pos = j & 31;
    int sb = r * 8 + x;
    int rem = NSB - r * 8;
    if (rem < 8) {
        int share = 8 / rem;
        int cap = 32 / share;
        sb = r * 8 + x / share;
        pos = (x % share) * cap + (pos % cap);
    }
    int sbr = sb / SBC, sbc = sb % SBC;
    rt = sbr * 4 + (pos >> 3);
    ct = sbc * 8 + (pos & 7);
}

// ---------------- transpose + fp32->bf16, 64x64 tiles, ushort4 writes
__global__ void tcvt64(const float* __restrict__ gw, const float* __restrict__ shg,
                       const float* __restrict__ uw, const float* __restrict__ shu,
                       const float* __restrict__ dw, const float* __restrict__ shd,
                       ushort_t* __restrict__ gwt, ushort_t* __restrict__ uwt,
                       ushort_t* __restrict__ dwt) {
    __shared__ float tile[64][65];
    int z = blockIdx.z;
    const float* src;
    ushort_t* dst;
    int R, C, bx = blockIdx.x, by = blockIdx.y;
    if (z < 18) {                       // gate/up: src [H][I], dst [I][H]
        int zz = z % 9;
        R = HDIM; C = IDIM;
        if (z < 9) { src = zz < 8 ? gw + (size_t)zz * HDIM * IDIM : shg; dst = gwt + (size_t)zz * IDIM * HDIM; }
        else       { src = zz < 8 ? uw + (size_t)zz * HDIM * IDIM : shu; dst = uwt + (size_t)zz * IDIM * HDIM; }
    } else {                            // down: src [I][H], dst [H][I]
        int zz = z - 18;
        R = IDIM; C = HDIM;
        src = zz < 8 ? dw + (size_t)zz * IDIM * HDIM : shd;
        dst = dwt + (size_t)zz * HDIM * IDIM;
        int t = bx; bx = by; by = t;
    }
    int c0 = bx * 64, r0 = by * 64;
    int tx = threadIdx.x, ty = threadIdx.y;       // (64,4)
#pragma unroll
    for (int i = 0; i < 16; ++i)
        tile[ty + i * 4][tx] = src[(size_t)(r0 + ty + i * 4) * C + c0 + tx];
    __syncthreads();
    int tid = ty * 64 + tx;
    int rr = (tid & 15) * 4, cc0 = tid >> 4;
#pragma unroll
    for (int it = 0; it < 4; ++it) {
        int c = cc0 + it * 16;
        ushort4 v;
        v.x = f2bf(tile[rr + 0][c]);
        v.y = f2bf(tile[rr + 1][c]);
        v.z = f2bf(tile[rr + 2][c]);
        v.w = f2bf(tile[rr + 3][c]);
        *(ushort4*)&dst[(size_t)(c0 + c) * R + r0 + rr] = v;
    }
}

// ---------------- layernorm + router
__global__ void ln_router(const float* __restrict__ x, const float* __restrict__ lnw,
                          const float* __restrict__ lnb, const float* __restrict__ rw,
                          ushort_t* __restrict__ normed, int* __restrict__ top_idx,
                          float* __restrict__ top_score, int* __restrict__ cnt) {
    int t = blockIdx.x, tid = threadIdx.x;
    const float* xr = x + (size_t)t * HDIM;
    float v[4];
    float s = 0.f, ss = 0.f;
#pragma unroll
    for (int i = 0; i < 4; i++) {
        v[i] = xr[tid + i * 256];
        s += v[i];
        ss += v[i] * v[i];
    }
#pragma unroll
    for (int o = 32; o; o >>= 1) {
        s += __shfl_down(s, o);
        ss += __shfl_down(ss, o);
    }
    __shared__ float rs_[4], rss_[4], stats[2];
    int wid = tid >> 6, lane = tid & 63;
    if (!lane) { rs_[wid] = s; rss_[wid] = ss; }
    __syncthreads();
    if (!tid) {
        float S = rs_[0] + rs_[1] + rs_[2] + rs_[3];
        float SS = rss_[0] + rss_[1] + rss_[2] + rss_[3];
        float mu = S * (1.f / HDIM);
        float var = SS * (1.f / HDIM) - mu * mu;
        stats[0] = mu;
        stats[1] = rsqrtf(var + 1e-5f);
    }
    __syncthreads();
    float mu = stats[0], rsg = stats[1];
    float lg[8] = {0, 0, 0, 0, 0, 0, 0, 0};
#pragma unroll
    for (int i = 0; i < 4; i++) {
        int h = tid + i * 256;
        float xn = (v[i] - mu) * rsg * lnw[h] + lnb[h];
        normed[(size_t)t * HDIM + h] = f2bf(xn);
        const float* rwh = rw + (size_t)h * NEXP;
#pragma unroll
        for (int e = 0; e < 8; e++) lg[e] += xn * rwh[e];
    }
#pragma unroll
    for (int o = 32; o; o >>= 1)
#pragma unroll
        for (int e = 0; e < 8; e++) lg[e] += __shfl_down(lg[e], o);
    __shared__ float lred[4][8];
    if (!lane)
#pragma unroll
        for (int e = 0; e < 8; e++) lred[wid][e] = lg[e];
    __syncthreads();
    if (!tid) {
        float best = -1e30f;
        int bi = 0;
#pragma unroll
        for (int e = 0; e < 8; e++) {
            float L = lred[0][e] + lred[1][e] + lred[2][e] + lred[3][e];
            if (L > best) { best = L; bi = e; }
        }
        top_idx[t] = bi;
        top_score[t] = 1.f / (1.f + __expf(-best));
        atomicAdd(&cnt[bi], 1);
    }
}

__global__ void scan_k(const int* __restrict__ cnt, int* __restrict__ pad_off,
                       int* __restrict__ fill) {
    if (threadIdx.x == 0) {
        int o = 0;
        for (int e = 0; e < NEXP; e++) {
            pad_off[e] = o;
            o += (cnt[e] + 255) & ~255;
        }
        pad_off[NEXP] = o;
    }
    if (threadIdx.x < NEXP) fill[threadIdx.x] = 0;
}

__global__ void scatter_k(const ushort_t* __restrict__ normed, const int* __restrict__ top_idx,
                          const float* __restrict__ top_score, const int* __restrict__ pad_off,
                          int* __restrict__ fill, int* __restrict__ order,
                          ushort_t* __restrict__ xs) {
    int t = blockIdx.x, tid = threadIdx.x;
    __shared__ int spos;
    if (!tid) {
        int e = top_idx[t];
        int p = pad_off[e] + atomicAdd(&fill[e], 1);
        order[p] = t;
        spos = p;
    }
    __syncthreads();
    int pos = spos;
    float sc = top_score[t];
    const ushort4* src = (const ushort4*)(normed + (size_t)t * HDIM);
    ushort4* dst = (ushort4*)(xs + (size_t)pos * HDIM);
    ushort4 a = src[tid];
    a.x = f2bf(b2f(a.x) * sc);
    a.y = f2bf(b2f(a.y) * sc);
    a.z = f2bf(b2f(a.z) * sc);
    a.w = f2bf(b2f(a.w) * sc);
    dst[tid] = a;
}

// ================= GEMM1 (round-8 known-good): hmid = silu(X@Wg^T)*(X@Wu^T)
// BM=256, BN=128g+128u, K-step 64, ring-2 (64KB buffers), ONE barrier/phase.
__global__ __launch_bounds__(512, 2) void gemm1_k(
    const ushort_t* __restrict__ X, const ushort_t* __restrict__ Wg,
    const ushort_t* __restrict__ Wu, const int* __restrict__ pad_off,
    ushort_t* __restrict__ hmid) {
    __shared__ __align__(16) ushort_t lds[2 * 32768];  // 128 KiB
    const int CT = IDIM / 128;                       // 16
    const int NH = HDIM / 64;                        // 16 phases
    int rt, ct;
    sbmap(blockIdx.x, CT / 8, (TOTROWS / 256 / 4) * (CT / 8), rt, ct);
    int row0 = rt * 256, col0 = ct * 128;
    int e;
    if (row0 >= RPAD_MAX) e = 8;
    else {
        if (row0 >= pad_off[NEXP]) return;
        e = 0;
        while (e < 7 && row0 >= pad_off[e + 1]) ++e;
    }
    const ushort_t* wgp = Wg + (size_t)e * IDIM * HDIM;
    const ushort_t* wup = Wu + (size_t)e * IDIM * HDIM;

    const int tid = threadIdx.x, l = tid & 63, w = tid >> 6;
    const int wm = w >> 2, wn = w & 3;
    const int lr = l & 15, lg4 = l >> 4;

    const ushort_t* sA[4];
#pragma unroll
    for (int j = 0; j < 4; ++j) {
        int gi = tid + j * 512, row = gi >> 3, kg = (gi & 7) ^ (row & 7);
        sA[j] = X + (size_t)(row0 + row) * HDIM + kg * 8;
    }
    const ushort_t *sBg[2], *sBu[2];
#pragma unroll
    for (int j = 0; j < 2; ++j) {
        int gi = tid + j * 512, row = gi >> 3, kg = (gi & 7) ^ (row & 7);
        sBg[j] = wgp + (size_t)(col0 + row) * HDIM + kg * 8;
        sBu[j] = wup + (size_t)(col0 + row) * HDIM + kg * 8;
    }
    const int sl0 = (lg4 ^ (lr & 7)) * 8, sl1 = ((4 + lg4) ^ (lr & 7)) * 8;
    const int aob = (wm * 128 + lr) * 64;
    const int bob = (wn * 32 + lr) * 64;

    f32x4 accg[8][2] = {};
    f32x4 accu[8][2] = {};

#define G1_STAGE(h) do { int ko = (h) * 64; int hb_ = ((h) & 1) * 32768;       \
        gload16(sA[0] + ko, &lds[hb_ + tid * 8]);                              \
        gload16(sA[1] + ko, &lds[hb_ + 4096 + tid * 8]);                       \
        gload16(sA[2] + ko, &lds[hb_ + 8192 + tid * 8]);                       \
        gload16(sA[3] + ko, &lds[hb_ + 12288 + tid * 8]);                      \
        gload16(sBg[0] + ko, &lds[hb_ + 16384 + tid * 8]);                     \
        gload16(sBg[1] + ko, &lds[hb_ + 20480 + tid * 8]);                     \
        gload16(sBu[0] + ko, &lds[hb_ + 24576 + tid * 8]);                     \
        gload16(sBu[1] + ko, &lds[hb_ + 28672 + tid * 8]); } while (0)

#define G1_PH(h, DOSTAGE) do {                                                 \
        const int hb = ((h) & 1) * 32768;                                      \
        s16x8 a0[8], a1[8], b0[4], b1[4];                                      \
        _Pragma("unroll")                                                      \
        for (int m = 0; m < 8; ++m) a0[m] = *(const s16x8*)&lds[hb + aob + m * 1024 + sl0]; \
        _Pragma("unroll")                                                      \
        for (int n = 0; n < 2; ++n) {                                          \
            b0[n] = *(const s16x8*)&lds[hb + 16384 + bob + n * 1024 + sl0];    \
            b0[2 + n] = *(const s16x8*)&lds[hb + 24576 + bob + n * 1024 + sl0]; \
        }                                                                      \
        SCHB();                                                                \
        _Pragma("unroll")                                                      \
        for (int m = 0; m < 8; ++m) a1[m] = *(const s16x8*)&lds[hb + aob + m * 1024 + sl1]; \
        _Pragma("unroll")                                                      \
        for (int n = 0; n < 2; ++n) {                                          \
            b1[n] = *(const s16x8*)&lds[hb + 16384 + bob + n * 1024 + sl1];    \
            b1[2 + n] = *(const s16x8*)&lds[hb + 24576 + bob + n * 1024 + sl1]; \
        }                                                                      \
        SCHB();                                                                \
        if (DOSTAGE) G1_STAGE((h) + 1);                                        \
        LGKM(12);                                                              \
        __builtin_amdgcn_s_setprio(1);                                         \
        _Pragma("unroll")                                                      \
        for (int m = 0; m < 8; ++m) {                                          \
            accg[m][0] = __builtin_amdgcn_mfma_f32_16x16x32_bf16(a0[m], b0[0], accg[m][0], 0, 0, 0); \
            accg[m][1] = __builtin_amdgcn_mfma_f32_16x16x32_bf16(a0[m], b0[1], accg[m][1], 0, 0, 0); \
            accu[m][0] = __builtin_amdgcn_mfma_f32_16x16x32_bf16(a0[m], b0[2], accu[m][0], 0, 0, 0); \
            accu[m][1] = __builtin_amdgcn_mfma_f32_16x16x32_bf16(a0[m], b0[3], accu[m][1], 0, 0, 0); \
        }                                                                      \
        __builtin_amdgcn_s_setprio(0);                                         \
        LGKM(0);                                                               \
        __builtin_amdgcn_s_setprio(1);                                         \
        _Pragma("unroll")                                                      \
        for (int m = 0; m < 8; ++m) {                                          \
            accg[m][0] = __builtin_amdgcn_mfma_f32_16x16x32_bf16(a1[m], b1[0], accg[m][0], 0, 0, 0); \
            accg[m][1] = __builtin_amdgcn_mfma_f32_16x16x32_bf16(a1[m], b1[1], accg[m][1], 0, 0, 0); \
            accu[m][0] = __builtin_amdgcn_mfma_f32_16x16x32_bf16(a1[m], b1[2], accu[m][0], 0, 0, 0); \
            accu[m][1] = __builtin_amdgcn_mfma_f32_16x16x32_bf16(a1[m], b1[3], accu[m][1], 0, 0, 0); \
        }                                                                      \
        __builtin_amdgcn_s_setprio(0);                                         \
        VMW(0);                                                                \
        SBAR();                                                                \
    } while (0)

    G1_STAGE(0);
    VMW(0);
    SBAR();
    for (int h = 0; h < NH - 1; ++h) G1_PH(h, 1);
    G1_PH(NH - 1, 0);

#pragma unroll
    for (int mf = 0; mf < 8; ++mf) {
        int row = row0 + wm * 128 + mf * 16 + lg4 * 4;
#pragma unroll
        for (int nf = 0; nf < 2; ++nf) {
            int col = col0 + wn * 32 + nf * 16 + lr;
#pragma unroll
            for (int rr = 0; rr < 4; ++rr) {
                float g = accg[mf][nf][rr], u = accu[mf][nf][rr];
                float val = g / (1.f + __expf(-g)) * u;
                hmid[(size_t)(row + rr) * IDIM + col] = f2bf(val);
            }
        }
    }
#undef G1_STAGE
#undef G1_PH
}

// ================= GEMM2 direct-register (NO LDS, no barriers):
// out = Hm @ Wd^T (+ hs). BM=256, BN=256, fragments loaded global->VGPR.
// A-frag = 16B contiguous at Hm[row][k0+(l>>4)*8]; B-frag likewise (both [N][K]).
// A rows shared by 4 wn-waves, B rows by 2 wm-waves -> L1 dedup; 2 waves/SIMD
// hide each other's load latency. Compiler schedules waitcnts.
template <int SHARED>
__global__ __launch_bounds__(512, 2) void gemm2d_k(
    const ushort_t* __restrict__ Hm, const ushort_t* __restrict__ Wd,
    const int* __restrict__ pad_off, const int* __restrict__ order,
    const float* __restrict__ hs, float* __restrict__ out, int RT) {
    const int CT = 4;                    // 1024 / 256
    int nwg = RT * CT;
    int bid = blockIdx.x;
    int q = nwg >> 3, r = nwg & 7;
    int xcd = bid & 7, idx = bid >> 3;
    int wg = (xcd < r ? xcd * (q + 1) : r * (q + 1) + (xcd - r) * q) + idx;
    int rt = wg / CT, ct = wg % CT;      // rt-major: neighbors share A panel
    int row0 = rt * 256, col0 = ct * 256;
    const ushort_t* wdp;
    if (SHARED) {
        wdp = Wd + (size_t)8 * HDIM * IDIM;
    } else {
        if (row0 >= pad_off[NEXP]) return;
        int e = 0;
        while (e < 7 && row0 >= pad_off[e + 1]) ++e;
        wdp = Wd + (size_t)e * HDIM * IDIM;
    }
    const int tid = threadIdx.x, l = tid & 63, w = tid >> 6;
    const int wm = w >> 2, wn = w & 3;
    const int lr = l & 15, lg4 = l >> 4;

    const ushort_t* ap = Hm + (size_t)(row0 + wm * 128 + lr) * IDIM + lg4 * 8;
    const ushort_t* bp = wdp + (size_t)(col0 + wn * 64 + lr) * IDIM + lg4 * 8;

    f32x4 acc[8][4] = {};

#pragma unroll 2
    for (int k = 0; k < IDIM; k += 32) {
        s16x8 a[8], b[4];
#pragma unroll
        for (int m = 0; m < 8; ++m)
            a[m] = *(const s16x8*)(ap + (size_t)m * 16 * IDIM + k);
#pragma unroll
        for (int n = 0; n < 4; ++n)
            b[n] = *(const s16x8*)(bp + (size_t)n * 16 * IDIM + k);
#pragma unroll
        for (int m = 0; m < 8; ++m)
#pragma unroll
            for (int n = 0; n < 4; ++n)
                acc[m][n] = __builtin_amdgcn_mfma_f32_16x16x32_bf16(a[m], b[n], acc[m][n], 0, 0, 0);
    }

#pragma unroll
    for (int mf = 0; mf < 8; ++mf) {
        int row = row0 + wm * 128 + mf * 16 + lg4 * 4;
#pragma unroll
        for (int rr = 0; rr < 4; ++rr) {
            int rw_ = row + rr;
            int tok;
            if (SHARED) tok = rw_;               // shared region rows == tokens
            else { tok = order[rw_]; if (tok < 0) continue; }
            size_t ob = (size_t)tok * HDIM;
#pragma unroll
            for (int nf = 0; nf < 4; ++nf) {
                int col = col0 + wn * 64 + nf * 16 + lr;
                if (SHARED) out[ob + col] += hs[ob + col] + acc[mf][nf][rr];
                else        out[ob + col] = acc[mf][nf][rr];
            }
        }
    }
}

extern "C" void kernel_launch(void* const* d_in, const int* in_sizes, int n_in,
                              void* d_out, int out_size, void* d_ws, size_t ws_size,
                              hipStream_t stream) {
    const float* hs = (const float*)d_in[0];
    const float* lnw = (const float*)d_in[1];
    const float* lnb = (const float*)d_in[2];
    const float* rw = (const float*)d_in[3];
    const float* gw = (const float*)d_in[4];
    const float* uw = (const float*)d_in[5];
    const float* dw = (const float*)d_in[6];
    const float* shg = (const float*)d_in[7];
    const float* shu = (const float*)d_in[8];
    const float* shd = (const float*)d_in[9];
    float* out = (float*)d_out;

    char* p = (char*)d_ws;
    auto alloc = [&](size_t bytes) {
        void* r = (void*)p;
        p += (bytes + 255) & ~(size_t)255;
        return r;
    };
    ushort_t* xsbuf = (ushort_t*)alloc((size_t)TOTROWS * HDIM * 2);   // routed rows + normed rows
    ushort_t* hmid = (ushort_t*)alloc((size_t)TOTROWS * IDIM * 2);
    ushort_t* gwt = (ushort_t*)alloc((size_t)9 * IDIM * HDIM * 2);    // experts 0-7 + shared(8)
    ushort_t* uwt = (ushort_t*)alloc((size_t)9 * IDIM * HDIM * 2);
    ushort_t* dwt = (ushort_t*)alloc((size_t)9 * HDIM * IDIM * 2);
    int* cnt = (int*)alloc(NEXP * 4);
    int* pad_off = (int*)alloc((NEXP + 1) * 4);
    int* fill = (int*)alloc(NEXP * 4);
    int* top_idx = (int*)alloc(T_TOK * 4);
    float* top_sc = (float*)alloc(T_TOK * 4);
    int* order = (int*)alloc(RPAD_MAX * 4);

    ushort_t* normed = xsbuf + (size_t)RPAD_MAX * HDIM;

    hipMemsetAsync(cnt, 0, NEXP * 4, stream);
    hipMemsetAsync(order, 0xFF, RPAD_MAX * 4, stream);
    hipMemsetAsync(xsbuf, 0, (size_t)RPAD_MAX * HDIM * 2, stream);   // zero pad rows

    // weights transpose+convert (27 matrices)
    tcvt64<<<dim3(IDIM / 64, HDIM / 64, 27), dim3(64, 4), 0, stream>>>(
        gw, shg, uw, shu, dw, shd, gwt, uwt, dwt);

    ln_router<<<T_TOK, 256, 0, stream>>>(hs, lnw, lnb, rw, normed, top_idx, top_sc, cnt);
    scan_k<<<1, 64, 0, stream>>>(cnt, pad_off, fill);
    scatter_k<<<T_TOK, 256, 0, stream>>>(normed, top_idx, top_sc, pad_off, fill, order, xsbuf);

    // fused gemm1 over routed (rows [0,RPAD_MAX)) + shared (rows [RPAD_MAX,TOTROWS))
    {
        int RT = TOTROWS / 256, CT = IDIM / 128;
        gemm1_k<<<RT * CT, 512, 0, stream>>>(xsbuf, gwt, uwt, pad_off, hmid);
    }
    // routed down-proj FIRST: out[tok] = acc (plain store; every token exactly once)
    {
        int RT = RPAD_MAX / 256;  // 40 -> 160 blocks
        gemm2d_k<0><<<RT * 4, 512, 0, stream>>>(
            hmid, dwt, pad_off, order, hs, out, RT);
    }
    // shared down-proj SECOND: out += hs + acc
    {
        int RT = T_TOK / 256;  // 32 -> 128 blocks
        gemm2d_k<1><<<RT * 4, 512, 0, stream>>>(
            hmid + (size_t)RPAD_MAX * IDIM, dwt, pad_off, order, hs, out, RT);
    }
}

// Round 11
// 561.587 us; speedup vs baseline: 1.4191x; 1.4191x over previous
//
#include <hip/hip_runtime.h>

typedef unsigned short ushort_t;
typedef unsigned int uint_t;

#define T_TOK 8192
#define HDIM 1024
#define IDIM 2048
#define NEXP 8
#define RPAD_MAX 10240                 // 8192 + 8*256 worst-case padded routed rows
#define TOTROWS (RPAD_MAX + T_TOK)     // 18432

using f32x4 = __attribute__((ext_vector_type(4))) float;
using s16x8 = __attribute__((ext_vector_type(8))) short;

#define SBAR() do { asm volatile("" ::: "memory"); __builtin_amdgcn_s_barrier(); asm volatile("" ::: "memory"); } while (0)
#define VMW(n) asm volatile("s_waitcnt vmcnt(" #n ")" ::: "memory")
#define LGKM(n) do { asm volatile("s_waitcnt lgkmcnt(" #n ")" ::: "memory"); __builtin_amdgcn_sched_barrier(0); } while (0)
#define SCHB() __builtin_amdgcn_sched_barrier(0)

__device__ __forceinline__ float b2f(ushort_t h) {
    return __uint_as_float(((uint_t)h) << 16);
}
__device__ __forceinline__ ushort_t f2bf(float f) {
    uint_t u = __float_as_uint(f);
    uint_t r = (u + 0x7FFFu + ((u >> 16) & 1u)) >> 16;
    return (ushort_t)r;
}
__device__ __forceinline__ void gload16(const void* g, void* l) {
    __builtin_amdgcn_global_load_lds(
        (const __attribute__((address_space(1))) void*)g,
        (__attribute__((address_space(3))) void*)l, 16, 0, 0);
}
// 2-D super-block scheduler (XCD locality): 4rt x 8ct rectangle per XCD round.
__device__ __forceinline__ void sbmap(int bid, int SBC, int NSB, int& rt, int& ct) {
    int x = bid & 7, j = bid >> 3;
    int r = j >> 5, pos = j & 31;
    int sb = r * 8 + x;
    int rem = NSB - r * 8;
    if (rem < 8) {
        int share = 8 / rem;
        int cap = 32 / share;
        sb = r * 8 + x / share;
        pos = (x % share) * cap + (pos % cap);
    }
    int sbr = sb / SBC, sbc = sb % SBC;
    rt = sbr * 4 + (pos >> 3);
    ct = sbc * 8 + (pos & 7);
}

// ---------------- transpose + fp32->bf16, 64x64 tiles, ushort4 writes
__global__ void tcvt64(const float* __restrict__ gw, const float* __restrict__ shg,
                       const float* __restrict__ uw, const float* __restrict__ shu,
                       const float* __restrict__ dw, const float* __restrict__ shd,
                       ushort_t* __restrict__ gwt, ushort_t* __restrict__ uwt,
                       ushort_t* __restrict__ dwt) {
    __shared__ float tile[64][65];
    int z = blockIdx.z;
    const float* src;
    ushort_t* dst;
    int R, C, bx = blockIdx.x, by = blockIdx.y;
    if (z < 18) {                       // gate/up: src [H][I], dst [I][H]
        int zz = z % 9;
        R = HDIM; C = IDIM;
        if (z < 9) { src = zz < 8 ? gw + (size_t)zz * HDIM * IDIM : shg; dst = gwt + (size_t)zz * IDIM * HDIM; }
        else       { src = zz < 8 ? uw + (size_t)zz * HDIM * IDIM : shu; dst = uwt + (size_t)zz * IDIM * HDIM; }
    } else {                            // down: src [I][H], dst [H][I]
        int zz = z - 18;
        R = IDIM; C = HDIM;
        src = zz < 8 ? dw + (size_t)zz * IDIM * HDIM : shd;
        dst = dwt + (size_t)zz * HDIM * IDIM;
        int t = bx; bx = by; by = t;
    }
    int c0 = bx * 64, r0 = by * 64;
    int tx = threadIdx.x, ty = threadIdx.y;       // (64,4)
#pragma unroll
    for (int i = 0; i < 16; ++i)
        tile[ty + i * 4][tx] = src[(size_t)(r0 + ty + i * 4) * C + c0 + tx];
    __syncthreads();
    int tid = ty * 64 + tx;
    int rr = (tid & 15) * 4, cc0 = tid >> 4;
#pragma unroll
    for (int it = 0; it < 4; ++it) {
        int c = cc0 + it * 16;
        ushort4 v;
        v.x = f2bf(tile[rr + 0][c]);
        v.y = f2bf(tile[rr + 1][c]);
        v.z = f2bf(tile[rr + 2][c]);
        v.w = f2bf(tile[rr + 3][c]);
        *(ushort4*)&dst[(size_t)(c0 + c) * R + r0 + rr] = v;
    }
}

// ---------------- layernorm + router
__global__ void ln_router(const float* __restrict__ x, const float* __restrict__ lnw,
                          const float* __restrict__ lnb, const float* __restrict__ rw,
                          ushort_t* __restrict__ normed, int* __restrict__ top_idx,
                          float* __restrict__ top_score, int* __restrict__ cnt) {
    int t = blockIdx.x, tid = threadIdx.x;
    const float* xr = x + (size_t)t * HDIM;
    float v[4];
    float s = 0.f, ss = 0.f;
#pragma unroll
    for (int i = 0; i < 4; i++) {
        v[i] = xr[tid + i * 256];
        s += v[i];
        ss += v[i] * v[i];
    }
#pragma unroll
    for (int o = 32; o; o >>= 1) {
        s += __shfl_down(s, o);
        ss += __shfl_down(ss, o);
    }
    __shared__ float rs_[4], rss_[4], stats[2];
    int wid = tid >> 6, lane = tid & 63;
    if (!lane) { rs_[wid] = s; rss_[wid] = ss; }
    __syncthreads();
    if (!tid) {
        float S = rs_[0] + rs_[1] + rs_[2] + rs_[3];
        float SS = rss_[0] + rss_[1] + rss_[2] + rss_[3];
        float mu = S * (1.f / HDIM);
        float var = SS * (1.f / HDIM) - mu * mu;
        stats[0] = mu;
        stats[1] = rsqrtf(var + 1e-5f);
    }
    __syncthreads();
    float mu = stats[0], rsg = stats[1];
    float lg[8] = {0, 0, 0, 0, 0, 0, 0, 0};
#pragma unroll
    for (int i = 0; i < 4; i++) {
        int h = tid + i * 256;
        float xn = (v[i] - mu) * rsg * lnw[h] + lnb[h];
        normed[(size_t)t * HDIM + h] = f2bf(xn);
        const float* rwh = rw + (size_t)h * NEXP;
#pragma unroll
        for (int e = 0; e < 8; e++) lg[e] += xn * rwh[e];
    }
#pragma unroll
    for (int o = 32; o; o >>= 1)
#pragma unroll
        for (int e = 0; e < 8; e++) lg[e] += __shfl_down(lg[e], o);
    __shared__ float lred[4][8];
    if (!lane)
#pragma unroll
        for (int e = 0; e < 8; e++) lred[wid][e] = lg[e];
    __syncthreads();
    if (!tid) {
        float best = -1e30f;
        int bi = 0;
#pragma unroll
        for (int e = 0; e < 8; e++) {
            float L = lred[0][e] + lred[1][e] + lred[2][e] + lred[3][e];
            if (L > best) { best = L; bi = e; }
        }
        top_idx[t] = bi;
        top_score[t] = 1.f / (1.f + __expf(-best));
        atomicAdd(&cnt[bi], 1);
    }
}

__global__ void scan_k(const int* __restrict__ cnt, int* __restrict__ pad_off,
                       int* __restrict__ fill) {
    if (threadIdx.x == 0) {
        int o = 0;
        for (int e = 0; e < NEXP; e++) {
            pad_off[e] = o;
            o += (cnt[e] + 255) & ~255;
        }
        pad_off[NEXP] = o;
    }
    if (threadIdx.x < NEXP) fill[threadIdx.x] = 0;
}

__global__ void scatter_k(const ushort_t* __restrict__ normed, const int* __restrict__ top_idx,
                          const float* __restrict__ top_score, const int* __restrict__ pad_off,
                          int* __restrict__ fill, int* __restrict__ order,
                          ushort_t* __restrict__ xs) {
    int t = blockIdx.x, tid = threadIdx.x;
    __shared__ int spos;
    if (!tid) {
        int e = top_idx[t];
        int p = pad_off[e] + atomicAdd(&fill[e], 1);
        order[p] = t;
        spos = p;
    }
    __syncthreads();
    int pos = spos;
    float sc = top_score[t];
    const ushort4* src = (const ushort4*)(normed + (size_t)t * HDIM);
    ushort4* dst = (ushort4*)(xs + (size_t)pos * HDIM);
    ushort4 a = src[tid];
    a.x = f2bf(b2f(a.x) * sc);
    a.y = f2bf(b2f(a.y) * sc);
    a.z = f2bf(b2f(a.z) * sc);
    a.w = f2bf(b2f(a.w) * sc);
    dst[tid] = a;
}

// ================= GEMM1 (round-8 known-good): hmid = silu(X@Wg^T)*(X@Wu^T)
// BM=256, BN=128g+128u, K-step 64, ring-2 (64KB buffers), ONE barrier/phase.
__global__ __launch_bounds__(512, 2) void gemm1_k(
    const ushort_t* __restrict__ X, const ushort_t* __restrict__ Wg,
    const ushort_t* __restrict__ Wu, const int* __restrict__ pad_off,
    ushort_t* __restrict__ hmid) {
    __shared__ __align__(16) ushort_t lds[2 * 32768];  // 128 KiB
    const int CT = IDIM / 128;                       // 16
    const int NH = HDIM / 64;                        // 16 phases
    int rt, ct;
    sbmap(blockIdx.x, CT / 8, (TOTROWS / 256 / 4) * (CT / 8), rt, ct);
    int row0 = rt * 256, col0 = ct * 128;
    int e;
    if (row0 >= RPAD_MAX) e = 8;
    else {
        if (row0 >= pad_off[NEXP]) return;
        e = 0;
        while (e < 7 && row0 >= pad_off[e + 1]) ++e;
    }
    const ushort_t* wgp = Wg + (size_t)e * IDIM * HDIM;
    const ushort_t* wup = Wu + (size_t)e * IDIM * HDIM;

    const int tid = threadIdx.x, l = tid & 63, w = tid >> 6;
    const int wm = w >> 2, wn = w & 3;
    const int lr = l & 15, lg4 = l >> 4;

    const ushort_t* sA[4];
#pragma unroll
    for (int j = 0; j < 4; ++j) {
        int gi = tid + j * 512, row = gi >> 3, kg = (gi & 7) ^ (row & 7);
        sA[j] = X + (size_t)(row0 + row) * HDIM + kg * 8;
    }
    const ushort_t *sBg[2], *sBu[2];
#pragma unroll
    for (int j = 0; j < 2; ++j) {
        int gi = tid + j * 512, row = gi >> 3, kg = (gi & 7) ^ (row & 7);
        sBg[j] = wgp + (size_t)(col0 + row) * HDIM + kg * 8;
        sBu[j] = wup + (size_t)(col0 + row) * HDIM + kg * 8;
    }
    const int sl0 = (lg4 ^ (lr & 7)) * 8, sl1 = ((4 + lg4) ^ (lr & 7)) * 8;
    const int aob = (wm * 128 + lr) * 64;
    const int bob = (wn * 32 + lr) * 64;

    f32x4 accg[8][2] = {};
    f32x4 accu[8][2] = {};

#define G1_STAGE(h) do { int ko = (h) * 64; int hb_ = ((h) & 1) * 32768;       \
        gload16(sA[0] + ko, &lds[hb_ + tid * 8]);                              \
        gload16(sA[1] + ko, &lds[hb_ + 4096 + tid * 8]);                       \
        gload16(sA[2] + ko, &lds[hb_ + 8192 + tid * 8]);                       \
        gload16(sA[3] + ko, &lds[hb_ + 12288 + tid * 8]);                      \
        gload16(sBg[0] + ko, &lds[hb_ + 16384 + tid * 8]);                     \
        gload16(sBg[1] + ko, &lds[hb_ + 20480 + tid * 8]);                     \
        gload16(sBu[0] + ko, &lds[hb_ + 24576 + tid * 8]);                     \
        gload16(sBu[1] + ko, &lds[hb_ + 28672 + tid * 8]); } while (0)

#define G1_PH(h, DOSTAGE) do {                                                 \
        const int hb = ((h) & 1) * 32768;                                      \
        s16x8 a0[8], a1[8], b0[4], b1[4];                                      \
        _Pragma("unroll")                                                      \
        for (int m = 0; m < 8; ++m) a0[m] = *(const s16x8*)&lds[hb + aob + m * 1024 + sl0]; \
        _Pragma("unroll")                                                      \
        for (int n = 0; n < 2; ++n) {                                          \
            b0[n] = *(const s16x8*)&lds[hb + 16384 + bob + n * 1024 + sl0];    \
            b0[2 + n] = *(const s16x8*)&lds[hb + 24576 + bob + n * 1024 + sl0]; \
        }                                                                      \
        SCHB();                                                                \
        _Pragma("unroll")                                                      \
        for (int m = 0; m < 8; ++m) a1[m] = *(const s16x8*)&lds[hb + aob + m * 1024 + sl1]; \
        _Pragma("unroll")                                                      \
        for (int n = 0; n < 2; ++n) {                                          \
            b1[n] = *(const s16x8*)&lds[hb + 16384 + bob + n * 1024 + sl1];    \
            b1[2 + n] = *(const s16x8*)&lds[hb + 24576 + bob + n * 1024 + sl1]; \
        }                                                                      \
        SCHB();                                                                \
        if (DOSTAGE) G1_STAGE((h) + 1);                                        \
        LGKM(12);                                                              \
        __builtin_amdgcn_s_setprio(1);                                         \
        _Pragma("unroll")                                                      \
        for (int m = 0; m < 8; ++m) {                                          \
            accg[m][0] = __builtin_amdgcn_mfma_f32_16x16x32_bf16(a0[m], b0[0], accg[m][0], 0, 0, 0); \
            accg[m][1] = __builtin_amdgcn_mfma_f32_16x16x32_bf16(a0[m], b0[1], accg[m][1], 0, 0, 0); \
            accu[m][0] = __builtin_amdgcn_mfma_f32_16x16x32_bf16(a0[m], b0[2], accu[m][0], 0, 0, 0); \
            accu[m][1] = __builtin_amdgcn_mfma_f32_16x16x32_bf16(a0[m], b0[3], accu[m][1], 0, 0, 0); \
        }                                                                      \
        __builtin_amdgcn_s_setprio(0);                                         \
        LGKM(0);                                                               \
        __builtin_amdgcn_s_setprio(1);                                         \
        _Pragma("unroll")                                                      \
        for (int m = 0; m < 8; ++m) {                                          \
            accg[m][0] = __builtin_amdgcn_mfma_f32_16x16x32_bf16(a1[m], b1[0], accg[m][0], 0, 0, 0); \
            accg[m][1] = __builtin_amdgcn_mfma_f32_16x16x32_bf16(a1[m], b1[1], accg[m][1], 0, 0, 0); \
            accu[m][0] = __builtin_amdgcn_mfma_f32_16x16x32_bf16(a1[m], b1[2], accu[m][0], 0, 0, 0); \
            accu[m][1] = __builtin_amdgcn_mfma_f32_16x16x32_bf16(a1[m], b1[3], accu[m][1], 0, 0, 0); \
        }                                                                      \
        __builtin_amdgcn_s_setprio(0);                                         \
        VMW(0);                                                                \
        SBAR();                                                                \
    } while (0)

    G1_STAGE(0);
    VMW(0);
    SBAR();
    for (int h = 0; h < NH - 1; ++h) G1_PH(h, 1);
    G1_PH(NH - 1, 0);

#pragma unroll
    for (int mf = 0; mf < 8; ++mf) {
        int row = row0 + wm * 128 + mf * 16 + lg4 * 4;
#pragma unroll
        for (int nf = 0; nf < 2; ++nf) {
            int col = col0 + wn * 32 + nf * 16 + lr;
#pragma unroll
            for (int rr = 0; rr < 4; ++rr) {
                float g = accg[mf][nf][rr], u = accu[mf][nf][rr];
                float val = g / (1.f + __expf(-g)) * u;
                hmid[(size_t)(row + rr) * IDIM + col] = f2bf(val);
            }
        }
    }
#undef G1_STAGE
#undef G1_PH
}

// ================= GEMM2: out = Hm @ Wd^T (+ hs). BM=256, BN=256, K-step 64,
// ring-2 (64KB buffers), gemm1-identical schedule. 8 waves 2Mx4N (wave 128x64).
// Grids: routed 160 blocks, shared 128 blocks -> both single-round, no tail.
template <int SHARED>
__global__ __launch_bounds__(512, 2) void gemm2_k(
    const ushort_t* __restrict__ Hm, const ushort_t* __restrict__ Wd,
    const int* __restrict__ pad_off, const int* __restrict__ order,
    const float* __restrict__ hs, float* __restrict__ out, int RT) {
    __shared__ __align__(16) ushort_t lds[2 * 32768];  // 128 KiB
    const int CT = 4;                    // 1024 / 256
    const int NH = IDIM / 64;            // 32 phases
    int nwg = RT * CT;
    int bid = blockIdx.x;
    int q = nwg >> 3, r = nwg & 7;
    int xcd = bid & 7, idx = bid >> 3;
    int wg = (xcd < r ? xcd * (q + 1) : r * (q + 1) + (xcd - r) * q) + idx;
    int rt = wg >> 2, ct = wg & 3;       // rt-major
    int row0 = rt * 256, col0 = ct * 256;
    const ushort_t* wdp;
    if (SHARED) {
        wdp = Wd + (size_t)8 * HDIM * IDIM;
    } else {
        if (row0 >= pad_off[NEXP]) return;
        int e = 0;
        while (e < 7 && row0 >= pad_off[e + 1]) ++e;
        wdp = Wd + (size_t)e * HDIM * IDIM;
    }
    const int tid = threadIdx.x, l = tid & 63, w = tid >> 6;
    const int wm = w >> 2, wn = w & 3;
    const int lr = l & 15, lg4 = l >> 4;

    const ushort_t* sA[4];
    const ushort_t* sB[4];
#pragma unroll
    for (int j = 0; j < 4; ++j) {
        int gi = tid + j * 512, row = gi >> 3, kg = (gi & 7) ^ (row & 7);
        sA[j] = Hm + (size_t)(row0 + row) * IDIM + kg * 8;
        sB[j] = wdp + (size_t)(col0 + row) * IDIM + kg * 8;
    }
    const int sl0 = (lg4 ^ (lr & 7)) * 8, sl1 = ((4 + lg4) ^ (lr & 7)) * 8;
    const int aob = (wm * 128 + lr) * 64;
    const int bob = (wn * 64 + lr) * 64;

    f32x4 acc[8][4] = {};

#define G2_STAGE(h) do { int ko = (h) * 64; int hb_ = ((h) & 1) * 32768;       \
        gload16(sA[0] + ko, &lds[hb_ + tid * 8]);                              \
        gload16(sA[1] + ko, &lds[hb_ + 4096 + tid * 8]);                       \
        gload16(sA[2] + ko, &lds[hb_ + 8192 + tid * 8]);                       \
        gload16(sA[3] + ko, &lds[hb_ + 12288 + tid * 8]);                      \
        gload16(sB[0] + ko, &lds[hb_ + 16384 + tid * 8]);                      \
        gload16(sB[1] + ko, &lds[hb_ + 20480 + tid * 8]);                      \
        gload16(sB[2] + ko, &lds[hb_ + 24576 + tid * 8]);                      \
        gload16(sB[3] + ko, &lds[hb_ + 28672 + tid * 8]); } while (0)

#define G2_PH(h, DOSTAGE) do {                                                 \
        const int hb = ((h) & 1) * 32768;                                      \
        s16x8 a0[8], a1[8], b0[4], b1[4];                                      \
        _Pragma("unroll")                                                      \
        for (int m = 0; m < 8; ++m) a0[m] = *(const s16x8*)&lds[hb + aob + m * 1024 + sl0]; \
        _Pragma("unroll")                                                      \
        for (int n = 0; n < 4; ++n) b0[n] = *(const s16x8*)&lds[hb + 16384 + bob + n * 1024 + sl0]; \
        SCHB();                                                                \
        _Pragma("unroll")                                                      \
        for (int m = 0; m < 8; ++m) a1[m] = *(const s16x8*)&lds[hb + aob + m * 1024 + sl1]; \
        _Pragma("unroll")                                                      \
        for (int n = 0; n < 4; ++n) b1[n] = *(const s16x8*)&lds[hb + 16384 + bob + n * 1024 + sl1]; \
        SCHB();                                                                \
        if (DOSTAGE) G2_STAGE((h) + 1);                                        \
        LGKM(12);                                                              \
        __builtin_amdgcn_s_setprio(1);                                         \
        _Pragma("unroll")                                                      \
        for (int m = 0; m < 8; ++m)                                            \
            _Pragma("unroll")                                                  \
            for (int n = 0; n < 4; ++n)                                        \
                acc[m][n] = __builtin_amdgcn_mfma_f32_16x16x32_bf16(a0[m], b0[n], acc[m][n], 0, 0, 0); \
        __builtin_amdgcn_s_setprio(0);                                         \
        LGKM(0);                                                               \
        __builtin_amdgcn_s_setprio(1);                                         \
        _Pragma("unroll")                                                      \
        for (int m = 0; m < 8; ++m)                                            \
            _Pragma("unroll")                                                  \
            for (int n = 0; n < 4; ++n)                                        \
                acc[m][n] = __builtin_amdgcn_mfma_f32_16x16x32_bf16(a1[m], b1[n], acc[m][n], 0, 0, 0); \
        __builtin_amdgcn_s_setprio(0);                                         \
        VMW(0);                                                                \
        SBAR();                                                                \
    } while (0)

    G2_STAGE(0);
    VMW(0);
    SBAR();
    for (int h = 0; h < NH - 1; ++h) G2_PH(h, 1);
    G2_PH(NH - 1, 0);

#pragma unroll
    for (int mf = 0; mf < 8; ++mf) {
        int row = row0 + wm * 128 + mf * 16 + lg4 * 4;
#pragma unroll
        for (int rr = 0; rr < 4; ++rr) {
            int rw_ = row + rr;
            int tok;
            if (SHARED) tok = rw_;               // shared region rows == tokens
            else { tok = order[rw_]; if (tok < 0) continue; }
            size_t ob = (size_t)tok * HDIM;
#pragma unroll
            for (int nf = 0; nf < 4; ++nf) {
                int col = col0 + wn * 64 + nf * 16 + lr;
                if (SHARED) out[ob + col] += hs[ob + col] + acc[mf][nf][rr];
                else        out[ob + col] = acc[mf][nf][rr];
            }
        }
    }
#undef G2_STAGE
#undef G2_PH
}

extern "C" void kernel_launch(void* const* d_in, const int* in_sizes, int n_in,
                              void* d_out, int out_size, void* d_ws, size_t ws_size,
                              hipStream_t stream) {
    const float* hs = (const float*)d_in[0];
    const float* lnw = (const float*)d_in[1];
    const float* lnb = (const float*)d_in[2];
    const float* rw = (const float*)d_in[3];
    const float* gw = (const float*)d_in[4];
    const float* uw = (const float*)d_in[5];
    const float* dw = (const float*)d_in[6];
    const float* shg = (const float*)d_in[7];
    const float* shu = (const float*)d_in[8];
    const float* shd = (const float*)d_in[9];
    float* out = (float*)d_out;

    char* p = (char*)d_ws;
    auto alloc = [&](size_t bytes) {
        void* r = (void*)p;
        p += (bytes + 255) & ~(size_t)255;
        return r;
    };
    ushort_t* xsbuf = (ushort_t*)alloc((size_t)TOTROWS * HDIM * 2);   // routed rows + normed rows
    ushort_t* hmid = (ushort_t*)alloc((size_t)TOTROWS * IDIM * 2);
    ushort_t* gwt = (ushort_t*)alloc((size_t)9 * IDIM * HDIM * 2);    // experts 0-7 + shared(8)
    ushort_t* uwt = (ushort_t*)alloc((size_t)9 * IDIM * HDIM * 2);
    ushort_t* dwt = (ushort_t*)alloc((size_t)9 * HDIM * IDIM * 2);
    int* cnt = (int*)alloc(NEXP * 4);
    int* pad_off = (int*)alloc((NEXP + 1) * 4);
    int* fill = (int*)alloc(NEXP * 4);
    int* top_idx = (int*)alloc(T_TOK * 4);
    float* top_sc = (float*)alloc(T_TOK * 4);
    int* order = (int*)alloc(RPAD_MAX * 4);

    ushort_t* normed = xsbuf + (size_t)RPAD_MAX * HDIM;

    hipMemsetAsync(cnt, 0, NEXP * 4, stream);
    hipMemsetAsync(order, 0xFF, RPAD_MAX * 4, stream);
    hipMemsetAsync(xsbuf, 0, (size_t)RPAD_MAX * HDIM * 2, stream);   // zero pad rows

    // weights transpose+convert (27 matrices)
    tcvt64<<<dim3(IDIM / 64, HDIM / 64, 27), dim3(64, 4), 0, stream>>>(
        gw, shg, uw, shu, dw, shd, gwt, uwt, dwt);

    ln_router<<<T_TOK, 256, 0, stream>>>(hs, lnw, lnb, rw, normed, top_idx, top_sc, cnt);
    scan_k<<<1, 64, 0, stream>>>(cnt, pad_off, fill);
    scatter_k<<<T_TOK, 256, 0, stream>>>(normed, top_idx, top_sc, pad_off, fill, order, xsbuf);

    // fused gemm1 over routed (rows [0,RPAD_MAX)) + shared (rows [RPAD_MAX,TOTROWS))
    {
        int RT = TOTROWS / 256, CT = IDIM / 128;
        gemm1_k<<<RT * CT, 512, 0, stream>>>(xsbuf, gwt, uwt, pad_off, hmid);
    }
    // routed down-proj FIRST: out[tok] = acc (plain store; every token exactly once)
    {
        int RT = RPAD_MAX / 256;  // 40 -> 160 blocks (single round)
        gemm2_k<0><<<RT * 4, 512, 0, stream>>>(
            hmid, dwt, pad_off, order, hs, out, RT);
    }
    // shared down-proj SECOND: out += hs + acc
    {
        int RT = T_TOK / 256;  // 32 -> 128 blocks (single round)
        gemm2_k<1><<<RT * 4, 512, 0, stream>>>(
            hmid + (size_t)RPAD_MAX * IDIM, dwt, pad_off, order, hs, out, RT);
    }
}